// Round 3
// baseline (318.674 us; speedup 1.0000x reference)
//
#include <hip/hip_runtime.h>
#include <hip/hip_bf16.h>

#define N_NODES 8192
#define D_FEAT 128
#define NWORDS 8   // 8 u64 words of band codes per node (64 bands x 8 bits)

typedef __bf16 bf16x8 __attribute__((ext_vector_type(8)));
typedef float f32x4 __attribute__((ext_vector_type(4)));
typedef unsigned long long u64;

// ---------------- Kernel 1: fused normalize + LSH band codes ----------------
// 512 threads, 16 nodes per block (grid = 512 blocks = 2 blocks/CU, 4 wv/SIMD).
// Phase 1 (norm): 32-lane group per node, float4 loads, shuffle reduce,
//   write bf16 zn (ushort4).
// Phase 2 (codes): wave w owns code word w (64 projections); lane =
//   projection-within-word so the whole u64 word is one __ballot.
//   z chunks are wave-uniform float4 loads (scalar-promotable, 16B each,
//   L2-hot); H reads lane-coalesced 256B segments. 16 independent
//   accumulators per wave give ample ILP; 4 waves/SIMD hide the rest.
__global__ __launch_bounds__(512, 4) void prep_kernel(const float* __restrict__ z,
                                                      const float* __restrict__ H,
                                                      unsigned short* __restrict__ zn,
                                                      u64* __restrict__ codes) {
  int tid = threadIdx.x;
  int base = blockIdx.x * 16;

  // --- norm phase: node = tid>>5, 32 lanes x float4 cover 128 feats ---
  {
    int n = tid >> 5, sub = tid & 31;
    const float4* row = (const float4*)(z + (size_t)(base + n) * D_FEAT);
    float4 v = row[sub];
    float ss = v.x * v.x + v.y * v.y + v.z * v.z + v.w * v.w;
#pragma unroll
    for (int off = 16; off > 0; off >>= 1) ss += __shfl_xor(ss, off);
    float inv = rsqrtf(ss);
    __hip_bfloat16 b0 = __float2bfloat16(v.x * inv);
    __hip_bfloat16 b1 = __float2bfloat16(v.y * inv);
    __hip_bfloat16 b2 = __float2bfloat16(v.z * inv);
    __hip_bfloat16 b3 = __float2bfloat16(v.w * inv);
    ushort4 o;
    o.x = *(unsigned short*)&b0; o.y = *(unsigned short*)&b1;
    o.z = *(unsigned short*)&b2; o.w = *(unsigned short*)&b3;
    *(ushort4*)&zn[(size_t)(base + n) * D_FEAT + sub * 4] = o;
  }

  // --- codes phase: wave w -> word w ---
  int w = tid >> 6, lane = tid & 63;
  int col = w * 64 + lane;
  const float4* z4 = (const float4*)z;  // node row = 32 float4

  float acc[16];
#pragma unroll
  for (int n = 0; n < 16; ++n) acc[n] = 0.f;

  for (int k4 = 0; k4 < 32; ++k4) {
    float4 h;
    h.x = H[(size_t)(k4 * 4 + 0) * 512 + col];
    h.y = H[(size_t)(k4 * 4 + 1) * 512 + col];
    h.z = H[(size_t)(k4 * 4 + 2) * 512 + col];
    h.w = H[(size_t)(k4 * 4 + 3) * 512 + col];
    float4 zv[16];
#pragma unroll
    for (int n = 0; n < 16; ++n) zv[n] = z4[(size_t)(base + n) * 32 + k4];
#pragma unroll
    for (int n = 0; n < 16; ++n)
      acc[n] += zv[n].x * h.x + zv[n].y * h.y + zv[n].z * h.z + zv[n].w * h.w;
  }

#pragma unroll
  for (int n = 0; n < 16; ++n) {
    u64 b = __ballot(acc[n] > 0.0f);
    if (lane == 0) codes[(size_t)(base + n) * NWORDS + w] = b;
  }
}

// ---------------- Kernel 2: S = zn zn^T tile + epilogue ----------------
// 128x128 output tile per block, 4 waves each computing a 64x64 sub-tile
// via 4x4 MFMA 16x16x32 bf16 tiles; K=128 fully unrolled.
// bf16 LDS tiles XOR-swizzled in 16B chunks (conflict-free b128 frag reads).
// Epilogue values (diag / s>0.75 / rare collide check) staged through the
// same 64 KB LDS as fp32, then written with NON-TEMPORAL dwordx4 stores:
// out streams through L2 exactly once, so nt keeps the 2 MB zn L2-resident
// for the other blocks' tile loads.
__global__ __launch_bounds__(256, 2) void sim_kernel(const unsigned short* __restrict__ zn,
                                                     const u64* __restrict__ codes,
                                                     float* __restrict__ out) {
  __shared__ __align__(16) unsigned char smem_raw[65536];
  unsigned short (*As)[128] = (unsigned short (*)[128])smem_raw;            // 32 KB
  unsigned short (*Bs)[128] = (unsigned short (*)[128])(smem_raw + 32768);  // 32 KB
  float* fS = (float*)smem_raw;                                             // 64 KB alias

  int tid = threadIdx.x;
  int bm = blockIdx.x, bn = blockIdx.y;

  const uint4* gA = (const uint4*)(zn + (size_t)bm * 128 * D_FEAT);
  const uint4* gB = (const uint4*)(zn + (size_t)bn * 128 * D_FEAT);
#pragma unroll
  for (int r = 0; r < 8; ++r) {
    int idx = tid + 256 * r;        // 16B-chunk index, 0..2047
    int row = idx >> 4, c16 = idx & 15;
    int cs = c16 ^ (row & 15);      // XOR swizzle
    ((uint4*)&As[row][0])[cs] = gA[idx];
    ((uint4*)&Bs[row][0])[cs] = gB[idx];
  }
  __syncthreads();

  int wv = tid >> 6, lane = tid & 63;
  int wm = (wv >> 1) * 64, wn = (wv & 1) * 64;
  int m16 = lane & 15, g = lane >> 4;

  f32x4 acc[4][4] = {};

#pragma unroll
  for (int kc = 0; kc < 4; ++kc) {
    bf16x8 fa[4], fb[4];
    int chunk = kc * 4 + g;
    int cs = (chunk ^ m16) * 8;     // row bases are multiples of 16 -> row&15 == m16
#pragma unroll
    for (int t = 0; t < 4; ++t) {
      fa[t] = *(const bf16x8*)&As[wm + t * 16 + m16][cs];
      fb[t] = *(const bf16x8*)&Bs[wn + t * 16 + m16][cs];
    }
#pragma unroll
    for (int tm = 0; tm < 4; ++tm)
#pragma unroll
      for (int tn = 0; tn < 4; ++tn)
        acc[tm][tn] = __builtin_amdgcn_mfma_f32_16x16x32_bf16(fa[tm], fb[tn], acc[tm][tn], 0, 0, 0);
  }

  __syncthreads();   // all waves done reading As/Bs before aliasing as fS

  // Epilogue phase 1: compute final values in C-layout, write fp32 tile to
  // swizzled LDS. C/D layout: col=lane&15, row=g*4+r (m89/m91 verified).
#pragma unroll
  for (int tm = 0; tm < 4; ++tm) {
#pragma unroll
    for (int tn = 0; tn < 4; ++tn) {
      int col = wn + tn * 16 + m16;           // tile-local col
      int j = bn * 128 + col;
      f32x4 c = acc[tm][tn];
#pragma unroll
      for (int r = 0; r < 4; ++r) {
        int row = wm + tm * 16 + g * 4 + r;   // tile-local row
        int i = bm * 128 + row;
        float s = c[r];
        float val = 0.0f;
        if (i == j) {
          val = 1.0f;
        } else if (s > 0.75f) {
          // rare path: check band-code collision (any equal byte in 64 bands)
          bool hit = false;
#pragma unroll
          for (int w = 0; w < NWORDS; ++w) {
            u64 x = codes[(size_t)i * NWORDS + w] ^ codes[(size_t)j * NWORDS + w];
            u64 hz = (x - 0x0101010101010101ULL) & ~x & 0x8080808080808080ULL;
            hit |= (hz != 0);
          }
          if (hit) val = s;
        }
        // float4-granular XOR swizzle: chunk' = (col>>2) ^ (row&31)
        fS[row * 128 + ((((col >> 2) ^ (row & 31)) << 2) | (col & 3))] = val;
      }
    }
  }
  __syncthreads();

  // Epilogue phase 2: coalesced non-temporal dwordx4 stores; each wave
  // covers 2 full rows (2 x 512B contiguous segments) per iteration.
#pragma unroll
  for (int r = 0; r < 16; ++r) {
    int slot = tid + 256 * r;                 // 0..4095 float4 slots
    int row = slot >> 5, chunk = slot & 31;
    f32x4 v = *(const f32x4*)&fS[row * 128 + ((chunk ^ (row & 31)) << 2)];
    __builtin_nontemporal_store(
        v, (f32x4*)&out[(size_t)(bm * 128 + row) * N_NODES + bn * 128 + chunk * 4]);
  }
}

extern "C" void kernel_launch(void* const* d_in, const int* in_sizes, int n_in,
                              void* d_out, int out_size, void* d_ws, size_t ws_size,
                              hipStream_t stream) {
  const float* z = (const float*)d_in[0];   // [8192, 128] fp32
  const float* H = (const float*)d_in[1];   // [128, 512] fp32
  // d_in[2] = edge_index, unused by the reference forward.
  float* out = (float*)d_out;               // [8192, 8192] fp32

  unsigned short* zn = (unsigned short*)d_ws;                               // 2 MB bf16
  u64* codes = (u64*)((char*)d_ws + (size_t)N_NODES * D_FEAT * 2);          // 512 KB

  prep_kernel<<<N_NODES / 16, 512, 0, stream>>>(z, H, zn, codes);
  sim_kernel<<<dim3(64, 64), 256, 0, stream>>>(zn, codes, out);
}

// Round 4
// 300.629 us; speedup vs baseline: 1.0600x; 1.0600x over previous
//
#include <hip/hip_runtime.h>
#include <hip/hip_bf16.h>

#define N_NODES 8192
#define D_FEAT 128

typedef __bf16 bf16x8 __attribute__((ext_vector_type(8)));
typedef float f32x4 __attribute__((ext_vector_type(4)));
typedef unsigned long long u64;

// ---- cold path: on-the-fly LSH band-collision check (never taken for the
// given Gaussian inputs: max off-diag cosine ~0.49 << 0.75). noinline keeps
// it out of the hot kernel's register/instruction budget.
__device__ __attribute__((noinline)) bool lsh_collide(
    const float* __restrict__ z, const float* __restrict__ H, int i, int j) {
  for (int b = 0; b < 64; ++b) {          // 64 bands x 8 bits
    unsigned ci = 0, cj = 0;
    for (int bit = 0; bit < 8; ++bit) {
      int col = b * 8 + bit;
      float di = 0.f, dj = 0.f;
      for (int k = 0; k < D_FEAT; ++k) {
        float h = H[(size_t)k * 512 + col];
        di += z[(size_t)i * D_FEAT + k] * h;
        dj += z[(size_t)j * D_FEAT + k] * h;
      }
      if (di > 0.f) ci |= (1u << bit);
      if (dj > 0.f) cj |= (1u << bit);
    }
    if (ci == cj) return true;
  }
  return false;
}

__device__ __forceinline__ unsigned pack_bf16x2(float x, float y) {
  __hip_bfloat16 bx = __float2bfloat16(x), by = __float2bfloat16(y);
  return (unsigned)(*(unsigned short*)&bx) |
         ((unsigned)(*(unsigned short*)&by) << 16);
}

// Single fused kernel: per 128x128 output tile,
//  phase 0: normalize the needed z rows -> bf16 LDS tiles (XOR-swizzled)
//  phase 1: 4 waves x 4x4 MFMA 16x16x32 bf16, K=128 unrolled
//  phase 2: epilogue values (diag / s>0.75 rare collide) -> fp32 LDS (aliased)
//  phase 3: coalesced dwordx4 stores (plain, through L2 — nt regressed in R3)
__global__ __launch_bounds__(256, 2) void sim_kernel(const float* __restrict__ z,
                                                     const float* __restrict__ H,
                                                     float* __restrict__ out) {
  __shared__ __align__(16) unsigned char smem_raw[65536];
  unsigned short (*As)[128] = (unsigned short (*)[128])smem_raw;            // 32 KB
  unsigned short (*Bs)[128] = (unsigned short (*)[128])(smem_raw + 32768);  // 32 KB
  float* fS = (float*)smem_raw;                                             // 64 KB alias

  int tid = threadIdx.x;
  int bm = blockIdx.x, bn = blockIdx.y;

  // ---- Phase 0: fused normalize. 2 threads per row; pass 0 = A rows (bm),
  // pass 1 = B rows (bn). Row sum via pair shuffle; writes swizzled 16B
  // chunks (4-way bank aliasing, acceptable).
  {
    int row = tid >> 1, half = tid & 1;
#pragma unroll
    for (int pass = 0; pass < 2; ++pass) {
      int gr = (pass ? bn : bm) * 128 + row;
      const float4* src = (const float4*)(z + (size_t)gr * D_FEAT + half * 64);
      float4 v[16];
#pragma unroll
      for (int c = 0; c < 16; ++c) v[c] = src[c];
      float ss = 0.f;
#pragma unroll
      for (int c = 0; c < 16; ++c)
        ss += v[c].x * v[c].x + v[c].y * v[c].y + v[c].z * v[c].z + v[c].w * v[c].w;
      ss += __shfl_xor(ss, 1);            // combine the two half-rows
      float inv = rsqrtf(ss);
      unsigned short (*T)[128] = pass ? Bs : As;
#pragma unroll
      for (int c = 0; c < 8; ++c) {
        float4 a = v[2 * c], b = v[2 * c + 1];
        uint4 o;
        o.x = pack_bf16x2(a.x * inv, a.y * inv);
        o.y = pack_bf16x2(a.z * inv, a.w * inv);
        o.z = pack_bf16x2(b.x * inv, b.y * inv);
        o.w = pack_bf16x2(b.z * inv, b.w * inv);
        int cg = half * 8 + c;            // chunk index within the row
        ((uint4*)&T[row][0])[cg ^ (row & 15)] = o;
      }
    }
  }
  __syncthreads();

  // ---- Phase 1: MFMA (identical to verified R2 structure) ----
  int wv = tid >> 6, lane = tid & 63;
  int wm = (wv >> 1) * 64, wn = (wv & 1) * 64;
  int m16 = lane & 15, g = lane >> 4;

  f32x4 acc[4][4] = {};

#pragma unroll
  for (int kc = 0; kc < 4; ++kc) {
    bf16x8 fa[4], fb[4];
    int chunk = kc * 4 + g;
    int cs = (chunk ^ m16) * 8;           // row bases multiples of 16 -> row&15 == m16
#pragma unroll
    for (int t = 0; t < 4; ++t) {
      fa[t] = *(const bf16x8*)&As[wm + t * 16 + m16][cs];
      fb[t] = *(const bf16x8*)&Bs[wn + t * 16 + m16][cs];
    }
#pragma unroll
    for (int tm = 0; tm < 4; ++tm)
#pragma unroll
      for (int tn = 0; tn < 4; ++tn)
        acc[tm][tn] = __builtin_amdgcn_mfma_f32_16x16x32_bf16(fa[tm], fb[tn], acc[tm][tn], 0, 0, 0);
  }

  __syncthreads();   // all waves done reading As/Bs before aliasing as fS

  // ---- Phase 2: epilogue in C-layout (col=lane&15, row=g*4+r), fp32 tile
  // into swizzled LDS.
#pragma unroll
  for (int tm = 0; tm < 4; ++tm) {
#pragma unroll
    for (int tn = 0; tn < 4; ++tn) {
      int col = wn + tn * 16 + m16;       // tile-local col
      int j = bn * 128 + col;
      f32x4 c = acc[tm][tn];
#pragma unroll
      for (int r = 0; r < 4; ++r) {
        int row = wm + tm * 16 + g * 4 + r;
        int i = bm * 128 + row;
        float s = c[r];
        float val = 0.0f;
        if (i == j) {
          val = 1.0f;
        } else if (s > 0.75f) {
          if (lsh_collide(z, H, i, j)) val = s;   // cold path
        }
        fS[row * 128 + ((((col >> 2) ^ (row & 31)) << 2) | (col & 3))] = val;
      }
    }
  }
  __syncthreads();

  // ---- Phase 3: coalesced dwordx4 stores; each instr covers 2 full rows
  // (2 x 512B contiguous segments).
#pragma unroll
  for (int r = 0; r < 16; ++r) {
    int slot = tid + 256 * r;             // 0..4095 float4 slots
    int row = slot >> 5, chunk = slot & 31;
    float4 v = *(const float4*)&fS[row * 128 + ((chunk ^ (row & 31)) << 2)];
    *(float4*)&out[(size_t)(bm * 128 + row) * N_NODES + bn * 128 + chunk * 4] = v;
  }
}

extern "C" void kernel_launch(void* const* d_in, const int* in_sizes, int n_in,
                              void* d_out, int out_size, void* d_ws, size_t ws_size,
                              hipStream_t stream) {
  const float* z = (const float*)d_in[0];   // [8192, 128] fp32
  const float* H = (const float*)d_in[1];   // [128, 512] fp32
  // d_in[2] = edge_index, unused by the reference forward.
  float* out = (float*)d_out;               // [8192, 8192] fp32
  (void)d_ws; (void)ws_size;

  sim_kernel<<<dim3(64, 64), 256, 0, stream>>>(z, H, out);
}